// Round 2
// baseline (3904.792 us; speedup 1.0000x reference)
//
#include <hip/hip_runtime.h>
#include <hip/hip_bf16.h>
#include <cstddef>
#include <cstdint>

// Problem constants
#define NB 32          // batch
#define NS 512         // seq len
#define ND 512         // d_model == hid
#define NG 2048        // 4*hid gate cols per layer

// ws layout (bytes)
#define NSLOT 8
#define H0_OFF   0                     // [8 slots][32768] bf16 frag-order h, layer0
#define H1_OFF   (NSLOT * 32768)      // 262144: same, layer1
#define FLAGS_OFF (2 * NSLOT * 32768) // 524288: int[512]: [L][m][slice*2+n]
#define CTRL_BYTES (FLAGS_OFF + 2048) // 526336 memset region
#define XWS_OFF  (1u << 20)           // bf16 frag-order x: 512*32*512*2 bytes
#define XWS_BYTES (512u * 32u * 512u * 2u)

typedef __attribute__((ext_vector_type(8))) short short8;
typedef __attribute__((ext_vector_type(8))) __bf16 bf16x8;
typedef __attribute__((ext_vector_type(4))) float f32x4;
typedef unsigned long long u64t;

static __device__ __forceinline__ unsigned short f2bf(float f) {
  __hip_bfloat16 h = __float2bfloat16(f);
  return __builtin_bit_cast(unsigned short, h);
}

static __device__ __forceinline__ short8 pack8(float4 a, float4 b) {
  short8 r;
  r[0] = (short)f2bf(a.x); r[1] = (short)f2bf(a.y);
  r[2] = (short)f2bf(a.z); r[3] = (short)f2bf(a.w);
  r[4] = (short)f2bf(b.x); r[5] = (short)f2bf(b.y);
  r[6] = (short)f2bf(b.z); r[7] = (short)f2bf(b.w);
  return r;
}

// ---------------- Kernel 1: fp32 embedding gather (output 1) ----------------
__global__ __launch_bounds__(256) void gather_f32(const int* __restrict__ src,
                                                  const float* __restrict__ emb,
                                                  float* __restrict__ out1) {
  int tid = blockIdx.x * 256 + threadIdx.x;   // float4 granules
  int bt = tid >> 7;                          // b*512 + t
  int k4 = (tid & 127) << 2;
  int s  = src[bt];
  float4 v = *reinterpret_cast<const float4*>(emb + (size_t)s * ND + k4);
  *reinterpret_cast<float4*>(out1 + (size_t)bt * ND + k4) = v;
}

// ------------- Kernel 2: bf16 x in MFMA A-fragment order (into ws) ----------
// element (t,b,k) -> byte ((t*16 + (k>>5))*2 + (b>>4))*1024 + ((k>>3)&3)*256 + (b&15)*16 + (k&7)*2
__global__ __launch_bounds__(256) void gather_xfrag(const int* __restrict__ src,
                                                    const float* __restrict__ emb,
                                                    unsigned char* __restrict__ xws) {
  int tid = blockIdx.x * 256 + threadIdx.x;   // 0 .. 262143
  int br = tid & 15;
  int mh = (tid >> 4) & 1;
  int kt = (tid >> 5) & 15;
  int t  = tid >> 9;
  int b  = mh * 16 + br;
  int s  = src[b * NS + t];
  const float* row = emb + (size_t)s * ND + kt * 32;
  unsigned char* base = xws + ((size_t)((t * 16 + kt) * 2 + mh)) * 1024 + br * 16;
#pragma unroll
  for (int qq = 0; qq < 4; ++qq) {
    float4 v0 = *reinterpret_cast<const float4*>(row + qq * 8);
    float4 v1 = *reinterpret_cast<const float4*>(row + qq * 8 + 4);
    *reinterpret_cast<short8*>(base + qq * 256) = pack8(v0, v1);
  }
}

// ---------------- Kernel 3: persistent 2-layer LSTM, barrier-free step loop --
// grid = 128 blocks: L = bid>>6, slice = bid&63 (8 units / 32 gate cols each).
// 4 waves per block = (m batch-half, n col-half); each wave: full-K 16x16 tile,
// gate cols reordered [i4 f4 g4 o4] so epilogue is in-wave (shfl butterflies).
// Sync: per-wave flags, relaxed atomics + explicit s_waitcnt vmcnt(0). No
// __syncthreads in the step loop, no release stores (avoids buffer_wbl2).
template<bool XWS>
__global__ __launch_bounds__(256, 1) void lstm_persist(
    const float* __restrict__ Wk, const float* __restrict__ Wr,
    const float* __restrict__ bias_g,
    const float* __restrict__ x_f32,          // gathered fp32 emb (fallback path)
    const unsigned char* __restrict__ xws,    // frag-order bf16 x
    unsigned char* ws, float* __restrict__ out0) {

  __shared__ __attribute__((aligned(16))) short WT[32 * 1032];

  const int tid   = threadIdx.x;
  const int bid   = blockIdx.x;
  const int L     = bid >> 6;
  const int slice = bid & 63;
  const int u0    = slice * 8;
  const int lane  = tid & 63;
  const int wv    = tid >> 6;
  const int m     = wv & 1;    // batch half (16 rows)
  const int n     = wv >> 1;   // col half (16 gate cols = 4 units x 4 gates)

  const float* WkL = Wk + (size_t)L * 512 * NG;
  const float* WrL = Wr + (size_t)L * 512 * NG;

  // ---- init: stage transposed weight slice into LDS: WT[32 cols][1032 k]
  // col c: n=c>>4, cc=c&15, gate=cc>>2, unit=u0 + (c>>4)*4 + (cc&3)
  for (int idx = tid; idx < 1024 * 32; idx += 256) {
    int k = idx >> 5, c = idx & 31;
    int cc = c & 15;
    int gc = (cc >> 2) * 512 + u0 + (c >> 4) * 4 + (cc & 3);
    float v = (k < 512) ? WkL[(size_t)k * NG + gc]
                        : WrL[(size_t)(k - 512) * NG + gc];
    WT[c * 1032 + k] = (short)f2bf(v);
  }
  __syncthreads();

  // ---- preload full-K B fragments for this wave's 16 cols (32 frags = 128 VGPRs)
  short8 Bf[32];
  {
    int colr = lane & 15, q = lane >> 4;
    const short* wcol = WT + (n * 16 + colr) * 1032 + q * 8;
#pragma unroll
    for (int kt = 0; kt < 32; ++kt)
      Bf[kt] = *reinterpret_cast<const short8*>(wcol + kt * 32);
  }
  const float bval = bias_g[L * NG + ((lane >> 2) & 3) * 512 + u0 + n * 4 + (lane & 3)];

  int* flags = reinterpret_cast<int*>(ws + FLAGS_OFF);
  unsigned char* h0r = ws + H0_OFF;
  unsigned char* h1r = ws + H1_OFF;
  unsigned char* myring = (L == 0) ? h0r : h1r;

  const int rg = lane >> 4;          // row group (4 batches)
  const int gl = (lane >> 2) & 3;    // gate index of this lane's column
  const int uu = lane & 3;           // unit-within-wave of this lane's column
  // h publish (uu==0 lanes): batch b = m*16 + rg*4 + gl, 4 units packed as u64
  const size_t pub_off = ((size_t)(u0 >> 5) * 2 + m) * 1024 +
                         ((u0 & 31) >> 3) * 256 + (size_t)(rg * 4 + gl) * 16 + n * 8;
  const int fbase0 = m * 128;        // layer0 flags for my batch half
  const int fbase1 = 256 + m * 128;  // layer1 flags for my batch half

  float cst[4] = {0.f, 0.f, 0.f, 0.f};
  bool gaveup = false;

  for (int t = 0; t < NS; ++t) {
    f32x4 acc[4];
#pragma unroll
    for (int i = 0; i < 4; ++i) acc[i] = (f32x4){0.f, 0.f, 0.f, 0.f};
    short8 af[16], af2[16];

    // ---- layer 0: x half (kt 0..15) is flag-independent — compute during wait
    if (L == 0) {
      if (XWS) {
        const unsigned char* xb = xws + ((size_t)t * 32 + m) * 1024 + (size_t)lane * 16;
#pragma unroll
        for (int kt = 0; kt < 16; ++kt)
          af[kt] = *reinterpret_cast<const short8*>(xb + (size_t)kt * 2048);
      } else {
        int bb = m * 16 + (lane & 15);
        const float* xr = x_f32 + ((size_t)bb * NS + t) * ND + (lane >> 4) * 8;
#pragma unroll
        for (int kt = 0; kt < 16; ++kt) {
          float4 v0 = *reinterpret_cast<const float4*>(xr + kt * 32);
          float4 v1 = *reinterpret_cast<const float4*>(xr + kt * 32 + 4);
          af[kt] = pack8(v0, v1);
        }
      }
#pragma unroll
      for (int kt = 0; kt < 16; ++kt)
        acc[kt & 3] = __builtin_amdgcn_mfma_f32_16x16x32_bf16(
            __builtin_bit_cast(bf16x8, af[kt]), __builtin_bit_cast(bf16x8, Bf[kt]),
            acc[kt & 3], 0, 0, 0);
    }

    // ---- poll per-wave flags (relaxed; all waves poll independently)
    // L0: h0[t-1] ready (flag0>=t) + ring anti-overwrite (flag1>=t-7)
    // L1: h0[t] ready (flag0>=t+1) + h1[t-1] ready (flag1>=t)
    if (!gaveup) {
      const int n0 = (L == 0) ? t : t + 1;
      const int n1 = (L == 0) ? t - (NSLOT - 1) : t;
      int spin = 0;
      for (;;) {
        int f0a = __hip_atomic_load(flags + fbase0 + lane,      __ATOMIC_RELAXED, __HIP_MEMORY_SCOPE_AGENT);
        int f0b = __hip_atomic_load(flags + fbase0 + 64 + lane, __ATOMIC_RELAXED, __HIP_MEMORY_SCOPE_AGENT);
        int f1a = __hip_atomic_load(flags + fbase1 + lane,      __ATOMIC_RELAXED, __HIP_MEMORY_SCOPE_AGENT);
        int f1b = __hip_atomic_load(flags + fbase1 + 64 + lane, __ATOMIC_RELAXED, __HIP_MEMORY_SCOPE_AGENT);
        if (__all(f0a >= n0 && f0b >= n0 && f1a >= n1 && f1b >= n1)) break;
        if (++spin > (1 << 18)) { gaveup = true; break; }
        __builtin_amdgcn_s_sleep(1);
      }
    }
    asm volatile("" ::: "memory");

    // ---- h fragment loads (agent-scope relaxed atomics -> IC) + MFMAs
    {
      const unsigned char* hb2 = myring + (size_t)((t - 1) & (NSLOT - 1)) * 32768 +
                                 (size_t)m * 1024 + (size_t)lane * 16;
      if (L == 1) {
        const unsigned char* hb1 = h0r + (size_t)(t & (NSLOT - 1)) * 32768 +
                                   (size_t)m * 1024 + (size_t)lane * 16;
#pragma unroll
        for (int kt = 0; kt < 16; ++kt) {
          u64t* ap = reinterpret_cast<u64t*>(&af[kt]);
          const u64t* p = reinterpret_cast<const u64t*>(hb1 + (size_t)kt * 2048);
          ap[0] = __hip_atomic_load(p,     __ATOMIC_RELAXED, __HIP_MEMORY_SCOPE_AGENT);
          ap[1] = __hip_atomic_load(p + 1, __ATOMIC_RELAXED, __HIP_MEMORY_SCOPE_AGENT);
        }
      }
#pragma unroll
      for (int kt = 0; kt < 16; ++kt) {
        u64t* ap = reinterpret_cast<u64t*>(&af2[kt]);
        const u64t* p = reinterpret_cast<const u64t*>(hb2 + (size_t)kt * 2048);
        ap[0] = __hip_atomic_load(p,     __ATOMIC_RELAXED, __HIP_MEMORY_SCOPE_AGENT);
        ap[1] = __hip_atomic_load(p + 1, __ATOMIC_RELAXED, __HIP_MEMORY_SCOPE_AGENT);
      }
      if (L == 1) {
#pragma unroll
        for (int kt = 0; kt < 16; ++kt)
          acc[kt & 3] = __builtin_amdgcn_mfma_f32_16x16x32_bf16(
              __builtin_bit_cast(bf16x8, af[kt]), __builtin_bit_cast(bf16x8, Bf[kt]),
              acc[kt & 3], 0, 0, 0);
      }
#pragma unroll
      for (int kt = 0; kt < 16; ++kt)
        acc[kt & 3] = __builtin_amdgcn_mfma_f32_16x16x32_bf16(
            __builtin_bit_cast(bf16x8, af2[kt]), __builtin_bit_cast(bf16x8, Bf[16 + kt]),
            acc[kt & 3], 0, 0, 0);
    }

    // ---- in-wave epilogue: gather 4 gates via shfl, LSTM cell update
    float hv[4];
    {
      const int lb = lane & ~12;
#pragma unroll
      for (int r = 0; r < 4; ++r) {
        float z = (acc[0][r] + acc[1][r]) + (acc[2][r] + acc[3][r]) + bval;
        float zi = __shfl(z, lb);
        float zf = __shfl(z, lb | 4);
        float zg = __shfl(z, lb | 8);
        float zo = __shfl(z, lb | 12);
        float ig = 1.f / (1.f + __expf(-zi));
        float fg = 1.f / (1.f + __expf(-zf));
        float e2 = __expf(-2.f * zg);
        float gg = (1.f - e2) / (1.f + e2);
        float og = 1.f / (1.f + __expf(-zo));
        cst[r] = fg * cst[r] + ig * gg;
        float ec = __expf(-2.f * cst[r]);
        hv[r] = og * (1.f - ec) / (1.f + ec);
      }
    }

    // ---- final output (layer 1): nontemporal fp32 stores (keep L2 clean)
    if (L == 1 && gl == 0) {
      float* op = out0 + ((size_t)(m * 16 + rg * 4) * NS + t) * ND + u0 + n * 4 + uu;
#pragma unroll
      for (int r = 0; r < 4; ++r)
        __builtin_nontemporal_store(hv[r], op + (size_t)r * NS * ND);
    }

    // ---- publish h: transpose in-wave so uu==0 lanes store 4 units as one u64
    {
      float tmp = (gl == 0) ? hv[0] : (gl == 1) ? hv[1] : (gl == 2) ? hv[2] : hv[3];
      unsigned int hb = f2bf(tmp);
      const int lb2 = lane & ~3;
      unsigned int p0 = (unsigned int)__shfl((int)hb, lb2);
      unsigned int p1 = (unsigned int)__shfl((int)hb, lb2 | 1);
      unsigned int p2 = (unsigned int)__shfl((int)hb, lb2 | 2);
      unsigned int p3 = (unsigned int)__shfl((int)hb, lb2 | 3);
      if (uu == 0) {
        u64t packed = (u64t)(p0 & 0xffffu)
                    | ((u64t)(p1 & 0xffffu) << 16)
                    | ((u64t)(p2 & 0xffffu) << 32)
                    | ((u64t)(p3 & 0xffffu) << 48);
        __hip_atomic_store(reinterpret_cast<u64t*>(
              myring + (size_t)(t & (NSLOT - 1)) * 32768 + pub_off),
            packed, __ATOMIC_RELAXED, __HIP_MEMORY_SCOPE_AGENT);
      }
    }

    // drain own wave's h stores to the coherence point, then relaxed flag store
    asm volatile("s_waitcnt vmcnt(0)" ::: "memory");
    if (lane == 0)
      __hip_atomic_store(flags + L * 256 + m * 128 + slice * 2 + n, t + 1,
                         __ATOMIC_RELAXED, __HIP_MEMORY_SCOPE_AGENT);
  }
}

extern "C" void kernel_launch(void* const* d_in, const int* in_sizes, int n_in,
                              void* d_out, int out_size, void* d_ws, size_t ws_size,
                              hipStream_t stream) {
  const int*   src = (const int*)d_in[0];
  // d_in[1] = source_len (unused by the reference computation)
  const float* emb = (const float*)d_in[2];
  const float* Wk  = (const float*)d_in[3];
  const float* Wr  = (const float*)d_in[4];
  const float* bg  = (const float*)d_in[5];

  float* out0 = (float*)d_out;                        // LSTM output [32,512,512]
  float* out1 = out0 + (size_t)NB * NS * ND;          // source_emb [32,512,512]
  unsigned char* ws = (unsigned char*)d_ws;

  // output 1: embedding gather (also the fp32 x source for the fallback path)
  gather_f32<<<8192, 256, 0, stream>>>(src, emb, out1);

  // zero flags + h rings every call (ws is re-poisoned by the harness)
  hipMemsetAsync(d_ws, 0, CTRL_BYTES, stream);

  bool xws_ok = ws_size >= (size_t)XWS_OFF + (size_t)XWS_BYTES;
  if (xws_ok) {
    gather_xfrag<<<1024, 256, 0, stream>>>(src, emb, ws + XWS_OFF);
    lstm_persist<true><<<128, 256, 0, stream>>>(Wk, Wr, bg, out1, ws + XWS_OFF, ws, out0);
  } else {
    lstm_persist<false><<<128, 256, 0, stream>>>(Wk, Wr, bg, out1, ws + XWS_OFF, ws, out0);
  }
}